// Round 10
// baseline (2881.614 us; speedup 1.0000x reference)
//
#include <hip/hip_runtime.h>
#include <hip/hip_bf16.h>

typedef __bf16 bf16_t;
typedef __bf16 bf16x8 __attribute__((ext_vector_type(8)));
typedef __bf16 bf16x4 __attribute__((ext_vector_type(4)));
typedef float  f32x4  __attribute__((ext_vector_type(4)));

static constexpr int ND = 768;
static constexpr int NH = 12;
static constexpr int NL = 12;
static constexpr int NF = 3072;
static constexpr int NB = 16;
static constexpr int NS = 512;
static constexpr int DH = 64;
static constexpr int MTOK = NB * NS;  // 8192 tokens

#define MFMA_BF16 __builtin_amdgcn_mfma_f32_16x16x32_bf16
#define FENCE() asm volatile("" ::: "memory")

__device__ __forceinline__ void gload16(const bf16_t* g, const bf16_t* l) {
    __builtin_amdgcn_global_load_lds(
        (const __attribute__((address_space(1))) void*)(unsigned long long)g,
        (__attribute__((address_space(3))) void*)(unsigned int)(unsigned long long)l,
        16, 0, 0);
}

// ---------------------------------------------------------------------------
__global__ __launch_bounds__(256) void embed_kernel(
    const int* __restrict__ tokens, const int* __restrict__ segments,
    const float* __restrict__ tok_emb, const float* __restrict__ seg_emb,
    const float* __restrict__ pos_emb, float* __restrict__ X,
    bf16_t* __restrict__ Xb)
{
    const int t = blockIdx.x;
    const int s = t & (NS - 1);
    const int tok = tokens[t], seg = segments[t];
    const float* te = tok_emb + (size_t)tok * ND;
    const float* se = seg_emb + (size_t)seg * ND;
    const float* pe = pos_emb + (size_t)s * ND;
#pragma unroll
    for (int i = 0; i < 3; ++i) {
        int d = threadIdx.x + i * 256;
        float v = te[d] + se[d] + pe[d];
        X[(size_t)t * ND + d]  = v;
        Xb[(size_t)t * ND + d] = (bf16_t)v;
    }
}

// ---------------------------------------------------------------------------
__global__ __launch_bounds__(256) void transpose_kernel(
    const float* __restrict__ src, bf16_t* __restrict__ dst,
    int K, int N, size_t src_stride, size_t dst_stride)
{
    __shared__ float tile[32][33];
    const float* s = src + blockIdx.z * src_stride;
    bf16_t*      d = dst + blockIdx.z * dst_stride;
    const int n0 = blockIdx.x * 32, k0 = blockIdx.y * 32;
#pragma unroll
    for (int i = threadIdx.y; i < 32; i += 8)
        tile[i][threadIdx.x] = s[(size_t)(k0 + i) * N + n0 + threadIdx.x];
    __syncthreads();
#pragma unroll
    for (int i = threadIdx.y; i < 32; i += 8)
        d[(size_t)(n0 + i) * K + k0 + threadIdx.x] = (bf16_t)tile[threadIdx.x][i];
}

__global__ __launch_bounds__(256) void concat_bias_kernel(
    const float* __restrict__ bq, const float* __restrict__ bk,
    const float* __restrict__ bv, float* __restrict__ fb)
{
    int idx = blockIdx.x * 256 + threadIdx.x;
    if (idx >= NL * 2304) return;
    int l = idx / 2304, c = idx % 2304;
    float v = (c < 768) ? bq[l * 768 + c]
            : (c < 1536) ? bk[l * 768 + c - 768] : bv[l * 768 + c - 1536];
    fb[idx] = v;
}

// ---------------------------------------------------------------------------
// GEMM v5: 128x128 tile, BK=64, 8 waves (2M x 4N of 64x32), 512 threads,
// dbuf global_load_lds (counted vmcnt(4)), both-sides XOR swizzle,
// XCD-chunked remap, setprio. 2 blocks/CU -> 16 waves/CU (4/SIMD).
//   MODE 2: o1 = bf16(v)        MODE 3: o1 = bf16(relu(v))
//   MODE 4: fused QKV epilogue (region-uniform; V via LDS transpose bounce)
// ---------------------------------------------------------------------------
template <int MODE>
__global__ __launch_bounds__(512, 4) void gemm_v5(
    const bf16_t* __restrict__ A, const bf16_t* __restrict__ Bt,
    const float* __restrict__ bias,
    bf16_t* __restrict__ o1, bf16_t* __restrict__ o2, bf16_t* __restrict__ o3,
    int K, int N, int gridN)
{
    __shared__ __align__(16) bf16_t smem[32768];  // 64 KB

    const int nwg = gridDim.x;
    const int l2 = (blockIdx.x & 7) * (nwg >> 3) + (blockIdx.x >> 3);
    const int m0 = (l2 / gridN) * 128, n0 = (l2 % gridN) * 128;

    const int tid = threadIdx.x, lane = tid & 63, wid = tid >> 6;
    const int wr = (wid >> 2) * 64, wc = (wid & 3) * 32;
    const int fr = lane & 15, g = lane >> 4;
    const int sr = lane >> 3;
    const int ssw = ((lane & 7) ^ sr) * 8;

    f32x4 acc[4][2] = {};
    const int nk = K >> 6;

    auto stage = [&](int buf, int kt) {
        const int k0 = kt << 6;
        bf16_t* Ad = smem + buf * 8192;
        bf16_t* Bd = smem + 16384 + buf * 8192;
#pragma unroll
        for (int i = 0; i < 2; ++i) {
            const int lr = i * 64 + wid * 8;
            gload16(A + (size_t)(m0 + lr + sr) * K + k0 + ssw, Ad + lr * 64);
        }
#pragma unroll
        for (int i = 0; i < 2; ++i) {
            const int lr = i * 64 + wid * 8;
            gload16(Bt + (size_t)(n0 + lr + sr) * K + k0 + ssw, Bd + lr * 64);
        }
    };

    stage(0, 0);
    for (int kt = 0; kt < nk; ++kt) {
        const int cur = kt & 1;
        if (kt + 1 < nk) {
            stage(cur ^ 1, kt + 1);
            asm volatile("s_waitcnt vmcnt(4)" ::: "memory");
        } else {
            asm volatile("s_waitcnt vmcnt(0)" ::: "memory");
        }
        FENCE(); __builtin_amdgcn_s_barrier(); FENCE();
        const bf16_t* Ab = smem + cur * 8192;
        const bf16_t* Bb = smem + 16384 + cur * 8192;
#pragma unroll
        for (int kk = 0; kk < 2; ++kk) {
            bf16x8 af[4], bfv[2];
#pragma unroll
            for (int m = 0; m < 4; ++m) {
                const int row = wr + m * 16 + fr;
                af[m] = *(const bf16x8*)(
                    &Ab[row * 64 + (((kk * 4 + g) ^ (fr & 7)) * 8)]);
            }
#pragma unroll
            for (int n = 0; n < 2; ++n) {
                const int row = wc + n * 16 + fr;
                bfv[n] = *(const bf16x8*)(
                    &Bb[row * 64 + (((kk * 4 + g) ^ (fr & 7)) * 8)]);
            }
            __builtin_amdgcn_s_setprio(1);
#pragma unroll
            for (int m = 0; m < 4; ++m)
#pragma unroll
                for (int n = 0; n < 2; ++n)
                    acc[m][n] = MFMA_BF16(af[m], bfv[n], acc[m][n], 0, 0, 0);
            __builtin_amdgcn_s_setprio(0);
        }
        FENCE(); __builtin_amdgcn_s_barrier(); FENCE();
    }

    const int rr = (lane >> 4) * 4, cc = lane & 15;

    if constexpr (MODE == 4) {
        if (n0 >= 1536) {
            // ---- V region: LDS transpose bounce -> coalesced [b][h][dh][s] ----
            bf16_t* vt = smem;  // 128 cols x 136-padded rows = 34.8 KB
#pragma unroll
            for (int m = 0; m < 4; ++m)
#pragma unroll
                for (int n = 0; n < 2; ++n) {
                    const int cl = wc + n * 16 + cc;
                    const float bv_ = bias[n0 + cl];
#pragma unroll
                    for (int j = 0; j < 4; ++j)
                        vt[cl * 136 + (wr + m * 16 + rr + j)] =
                            (bf16_t)(acc[m][n][j] + bv_);
                }
            __syncthreads();
            const int r = tid >> 2, q = tid & 3;
            const int c = n0 - 1536 + r;
            const int hh = c >> 6, dh = c & (DH - 1);
            const int b = m0 >> 9, s0 = m0 & (NS - 1);
            bf16_t* dst = o3 + (((size_t)(b * NH + hh)) * DH + dh) * NS + s0 + q * 32;
            const bf16_t* srcp = vt + r * 136 + q * 32;
#pragma unroll
            for (int k2 = 0; k2 < 4; ++k2)
                *(bf16x8*)(dst + k2 * 8) = *(const bf16x8*)(srcp + k2 * 8);
            return;
        }
        // ---- Q or K region: direct coalesced store ----
        bf16_t* dst = (n0 < 768) ? o1 : o2;
        const int nadj = (n0 < 768) ? n0 : n0 - 768;
#pragma unroll
        for (int m = 0; m < 4; ++m)
#pragma unroll
            for (int n = 0; n < 2; ++n)
#pragma unroll
                for (int j = 0; j < 4; ++j) {
                    const int row = m0 + wr + m * 16 + rr + j;
                    const int col = wc + n * 16 + cc;
                    dst[(size_t)row * 768 + nadj + col] =
                        (bf16_t)(acc[m][n][j] + bias[n0 + col]);
                }
        return;
    }

#pragma unroll
    for (int m = 0; m < 4; ++m)
#pragma unroll
        for (int n = 0; n < 2; ++n)
#pragma unroll
            for (int j = 0; j < 4; ++j) {
                const int row = m0 + wr + m * 16 + rr + j;
                const int col = n0 + wc + n * 16 + cc;
                const float v = acc[m][n][j] + bias[col];
                const size_t idx = (size_t)row * N + col;
                if constexpr (MODE == 2) {
                    o1[idx] = (bf16_t)v;
                } else {  // MODE 3
                    o1[idx] = (bf16_t)fmaxf(v, 0.0f);
                }
            }
}

// ---------------------------------------------------------------------------
// Flash attention: block = 128 q-rows of one (b,h); 4 waves x 32 rows.
// ---------------------------------------------------------------------------
__global__ __launch_bounds__(256) void attn_kernel(
    const bf16_t* __restrict__ Q, const bf16_t* __restrict__ K,
    const bf16_t* __restrict__ Vt, const int* __restrict__ vlens,
    bf16_t* __restrict__ O)
{
    const int h = blockIdx.x, b = blockIdx.y, qb = blockIdx.z;
    const int wid = threadIdx.x >> 6, lane = threadIdx.x & 63;
    const int q0 = qb * 128 + wid * 32;
    const int vl = vlens[b];
    const int fr = lane & 15, g = lane >> 4, g8 = g * 8;

    __shared__ __align__(16) bf16_t Ks[2][64 * 64];
    __shared__ __align__(16) bf16_t Vs[2][64 * 64];
    __shared__ __align__(16) bf16_t Plds[4][32 * 72];
    bf16_t* pl = Plds[wid];

    const bf16_t* kbase = K + ((size_t)(b * NS) * ND + h * DH);
    const bf16_t* vbase = Vt + ((size_t)(b * NH + h) * DH) * NS;  // [dh][s]

    bf16x8 qf[2][2];
#pragma unroll
    for (int qg = 0; qg < 2; ++qg) {
        const bf16_t* qptr = Q + ((size_t)(b * NS + q0 + qg * 16 + fr) * ND + h * DH);
        qf[qg][0] = *(const bf16x8*)(qptr + g8);
        qf[qg][1] = *(const bf16x8*)(qptr + 32 + g8);
    }
    asm volatile("s_waitcnt vmcnt(0)" ::: "memory");

    f32x4 acc_o[2][4] = {};
    float mrow[2][4], lrow[2][4];
#pragma unroll
    for (int qg = 0; qg < 2; ++qg)
#pragma unroll
        for (int j = 0; j < 4; ++j) { mrow[qg][j] = -1e30f; lrow[qg][j] = 0.f; }

    auto stage = [&](int buf, int t) {
        const int kv0 = t * 64;
#pragma unroll
        for (int i = 0; i < 2; ++i) {
            const int lr = wid * 16 + i * 8;
            const int r  = lr + (lane >> 3);
            const int ss = ((lane & 7) ^ (r & 7)) * 8;
            gload16(kbase + (size_t)(kv0 + r) * ND + ss, &Ks[buf][lr * 64]);
            gload16(vbase + (size_t)r * NS + kv0 + ss,   &Vs[buf][lr * 64]);
        }
    };

    stage(0, 0);
    for (int t = 0; t < 8; ++t) {
        const int cur = t & 1;
        const int kv0 = t * 64;
        if (t < 7) {
            stage(cur ^ 1, t + 1);
            asm volatile("s_waitcnt vmcnt(4)" ::: "memory");
        } else {
            asm volatile("s_waitcnt vmcnt(0)" ::: "memory");
        }
        FENCE(); __builtin_amdgcn_s_barrier(); FENCE();

        const bf16_t* ks = Ks[cur];
        const bf16_t* vs = Vs[cur];

        f32x4 sc[2][4];
#pragma unroll
        for (int qg = 0; qg < 2; ++qg)
#pragma unroll
            for (int f = 0; f < 4; ++f) sc[qg][f] = (f32x4){0.f, 0.f, 0.f, 0.f};
        __builtin_amdgcn_s_setprio(1);
#pragma unroll
        for (int f = 0; f < 4; ++f) {
            const int row = f * 16 + fr;
            const bf16_t* kr = ks + row * 64;
            bf16x8 kf0 = *(const bf16x8*)(kr + ((g ^ (row & 7)) * 8));
            bf16x8 kf1 = *(const bf16x8*)(kr + (((g + 4) ^ (row & 7)) * 8));
            sc[0][f] = MFMA_BF16(qf[0][0], kf0, sc[0][f], 0, 0, 0);
            sc[0][f] = MFMA_BF16(qf[0][1], kf1, sc[0][f], 0, 0, 0);
            sc[1][f] = MFMA_BF16(qf[1][0], kf0, sc[1][f], 0, 0, 0);
            sc[1][f] = MFMA_BF16(qf[1][1], kf1, sc[1][f], 0, 0, 0);
        }
        __builtin_amdgcn_s_setprio(0);

#pragma unroll
        for (int qg = 0; qg < 2; ++qg) {
            float sv[16];
#pragma unroll
            for (int f = 0; f < 4; ++f) {
                const int col = kv0 + f * 16 + fr;
                const bool masked = col >= vl;
#pragma unroll
                for (int j = 0; j < 4; ++j)
                    sv[f * 4 + j] = masked ? -1e6f : sc[qg][f][j] * 0.125f;
            }
            float pm[4], rs[4], scl[4];
#pragma unroll
            for (int j = 0; j < 4; ++j)
                pm[j] = fmaxf(fmaxf(sv[j], sv[4 + j]), fmaxf(sv[8 + j], sv[12 + j]));
#pragma unroll
            for (int msk = 1; msk < 16; msk <<= 1)
#pragma unroll
                for (int j = 0; j < 4; ++j) pm[j] = fmaxf(pm[j], __shfl_xor(pm[j], msk));
#pragma unroll
            for (int j = 0; j < 4; ++j) {
                const float mnew = fmaxf(mrow[qg][j], pm[j]);
                scl[j] = __expf(mrow[qg][j] - mnew);
                mrow[qg][j] = mnew;
                rs[j] = 0.f;
            }
#pragma unroll
            for (int f = 0; f < 4; ++f)
#pragma unroll
                for (int j = 0; j < 4; ++j) {
                    const float pv = __expf(sv[f * 4 + j] - mrow[qg][j]);
                    rs[j] += pv;
                    pl[(qg * 16 + g * 4 + j) * 72 + f * 16 + fr] = (bf16_t)pv;
                }
#pragma unroll
            for (int msk = 1; msk < 16; msk <<= 1)
#pragma unroll
                for (int j = 0; j < 4; ++j) rs[j] += __shfl_xor(rs[j], msk);
#pragma unroll
            for (int j = 0; j < 4; ++j) {
                lrow[qg][j] = lrow[qg][j] * scl[j] + rs[j];
#pragma unroll
                for (int n = 0; n < 4; ++n) acc_o[qg][n][j] *= scl[j];
            }
        }

        bf16x8 pf[2][2];
#pragma unroll
        for (int qg = 0; qg < 2; ++qg)
#pragma unroll
            for (int c = 0; c < 2; ++c)
                pf[qg][c] = *(const bf16x8*)(pl + (qg * 16 + fr) * 72 + c * 32 + g8);
        __builtin_amdgcn_s_setprio(1);
#pragma unroll
        for (int n = 0; n < 4; ++n) {
            const int row = n * 16 + fr;
            const bf16_t* vr = vs + row * 64;
            bf16x8 vf0 = *(const bf16x8*)(vr + ((g ^ (row & 7)) * 8));
            bf16x8 vf1 = *(const bf16x8*)(vr + (((g + 4) ^ (row & 7)) * 8));
            acc_o[0][n] = MFMA_BF16(pf[0][0], vf0, acc_o[0][n], 0, 0, 0);
            acc_o[0][n] = MFMA_BF16(pf[0][1], vf1, acc_o[0][n], 0, 0, 0);
            acc_o[1][n] = MFMA_BF16(pf[1][0], vf0, acc_o[1][n], 0, 0, 0);
            acc_o[1][n] = MFMA_BF16(pf[1][1], vf1, acc_o[1][n], 0, 0, 0);
        }
        __builtin_amdgcn_s_setprio(0);

        FENCE(); __builtin_amdgcn_s_barrier(); FENCE();
    }

#pragma unroll
    for (int qg = 0; qg < 2; ++qg)
#pragma unroll
        for (int n = 0; n < 4; ++n)
#pragma unroll
            for (int j = 0; j < 4; ++j) {
                const int row = q0 + qg * 16 + g * 4 + j;
                O[(size_t)(b * NS + row) * ND + h * DH + n * 16 + fr] =
                    (bf16_t)(acc_o[qg][n][j] / lrow[qg][j]);
            }
}

// ---------------------------------------------------------------------------
// Fused residual-add + LayerNorm: 1 wave per token.
// x = X + (float)Yb; stats; X = y (f32), Xb = bf16(y).
// ---------------------------------------------------------------------------
__global__ __launch_bounds__(256) void ln_kernel(
    const bf16_t* __restrict__ Yb, const float* __restrict__ g,
    const float* __restrict__ bt, float* __restrict__ X, bf16_t* __restrict__ Xb)
{
    const int wid = threadIdx.x >> 6, lane = threadIdx.x & 63;
    const int t = blockIdx.x * 4 + wid;

    const bf16_t* yp = Yb + (size_t)t * ND + lane * 12;
    bf16x4 ya = *(const bf16x4*)(yp);
    bf16x4 yb_ = *(const bf16x4*)(yp + 4);
    bf16x4 yc = *(const bf16x4*)(yp + 8);

    float* xp = X + (size_t)t * ND + lane * 12;
    f32x4 v0 = *(const f32x4*)(xp);
    f32x4 v1 = *(const f32x4*)(xp + 4);
    f32x4 v2 = *(const f32x4*)(xp + 8);

    float x[12];
#pragma unroll
    for (int i = 0; i < 4; ++i) {
        x[i]     = v0[i] + (float)ya[i];
        x[4 + i] = v1[i] + (float)yb_[i];
        x[8 + i] = v2[i] + (float)yc[i];
    }

    float s = 0.f, ss = 0.f;
#pragma unroll
    for (int i = 0; i < 12; ++i) { s += x[i]; ss += x[i] * x[i]; }
#pragma unroll
    for (int m = 1; m < 64; m <<= 1) {
        s += __shfl_xor(s, m);
        ss += __shfl_xor(ss, m);
    }
    const float mean = s * (1.0f / ND);
    const float var = ss * (1.0f / ND) - mean * mean;
    const float inv = rsqrtf(var + 1e-5f);

    const float* gp = g + lane * 12;
    const float* bp = bt + lane * 12;
    f32x4 g0 = *(const f32x4*)(gp), g1 = *(const f32x4*)(gp + 4),
          g2 = *(const f32x4*)(gp + 8);
    f32x4 b0 = *(const f32x4*)(bp), b1 = *(const f32x4*)(bp + 4),
          b2 = *(const f32x4*)(bp + 8);

    float y[12];
#pragma unroll
    for (int i = 0; i < 4; ++i) {
        y[i]     = (x[i]     - mean) * inv * g0[i] + b0[i];
        y[4 + i] = (x[4 + i] - mean) * inv * g1[i] + b1[i];
        y[8 + i] = (x[8 + i] - mean) * inv * g2[i] + b2[i];
    }

    f32x4 o0, o1v, o2v;
#pragma unroll
    for (int i = 0; i < 4; ++i) { o0[i] = y[i]; o1v[i] = y[4 + i]; o2v[i] = y[8 + i]; }
    *(f32x4*)(xp)     = o0;
    *(f32x4*)(xp + 4) = o1v;
    *(f32x4*)(xp + 8) = o2v;

    bf16x4 q0, q1, q2;
#pragma unroll
    for (int i = 0; i < 4; ++i) {
        q0[i] = (bf16_t)y[i]; q1[i] = (bf16_t)y[4 + i]; q2[i] = (bf16_t)y[8 + i];
    }
    bf16_t* xb = Xb + (size_t)t * ND + lane * 12;
    *(bf16x4*)(xb)     = q0;
    *(bf16x4*)(xb + 4) = q1;
    *(bf16x4*)(xb + 8) = q2;
}

// ---------------------------------------------------------------------------
extern "C" void kernel_launch(void* const* d_in, const int* in_sizes, int n_in,
                              void* d_out, int out_size, void* d_ws, size_t ws_size,
                              hipStream_t stream)
{
    (void)in_sizes; (void)n_in; (void)out_size; (void)ws_size;
    const int*   tokens   = (const int*)d_in[0];
    const int*   segments = (const int*)d_in[1];
    const int*   vlens    = (const int*)d_in[2];
    const float* tok_emb  = (const float*)d_in[3];
    const float* seg_emb  = (const float*)d_in[4];
    const float* pos_emb  = (const float*)d_in[5];
    const float* Wq = (const float*)d_in[6];  const float* bq = (const float*)d_in[7];
    const float* Wk = (const float*)d_in[8];  const float* bk = (const float*)d_in[9];
    const float* Wv = (const float*)d_in[10]; const float* bv = (const float*)d_in[11];
    const float* Wo = (const float*)d_in[12]; const float* bo = (const float*)d_in[13];
    const float* W1 = (const float*)d_in[14]; const float* b1 = (const float*)d_in[15];
    const float* W2 = (const float*)d_in[16]; const float* b2 = (const float*)d_in[17];
    const float* g1 = (const float*)d_in[18]; const float* be1 = (const float*)d_in[19];
    const float* g2 = (const float*)d_in[20]; const float* be2 = (const float*)d_in[21];

    float* X = (float*)d_out;

    char* p = (char*)d_ws;
    auto carve = [&](size_t elems, size_t esz) {
        void* r = (void*)p;
        p += (elems * esz + 255) & ~(size_t)255;
        return r;
    };
    bf16_t* wqkvT = (bf16_t*)carve((size_t)NL * 2304 * ND, 2);
    bf16_t* woT   = (bf16_t*)carve((size_t)NL * ND * ND, 2);
    bf16_t* w1T   = (bf16_t*)carve((size_t)NL * NF * ND, 2);
    bf16_t* w2T   = (bf16_t*)carve((size_t)NL * ND * NF, 2);
    float*  fb    = (float*)carve((size_t)NL * 2304, 4);
    bf16_t* Xb    = (bf16_t*)carve((size_t)MTOK * ND, 2);
    bf16_t* Qb    = (bf16_t*)carve((size_t)MTOK * ND, 2);
    bf16_t* Kb    = (bf16_t*)carve((size_t)MTOK * ND, 2);
    bf16_t* Vtb   = (bf16_t*)carve((size_t)MTOK * ND, 2);
    bf16_t* Ob    = (bf16_t*)carve((size_t)MTOK * ND, 2);
    bf16_t* H1    = (bf16_t*)carve((size_t)MTOK * NF, 2);
    bf16_t* Yb    = (bf16_t*)carve((size_t)MTOK * ND, 2);

    embed_kernel<<<MTOK, 256, 0, stream>>>(tokens, segments, tok_emb, seg_emb,
                                           pos_emb, X, Xb);
    const dim3 tb(32, 8);
    const size_t qkvs = (size_t)2304 * ND;
    transpose_kernel<<<dim3(ND / 32, ND / 32, NL), tb, 0, stream>>>(
        Wq, wqkvT, ND, ND, (size_t)ND * ND, qkvs);
    transpose_kernel<<<dim3(ND / 32, ND / 32, NL), tb, 0, stream>>>(
        Wk, wqkvT + (size_t)768 * ND, ND, ND, (size_t)ND * ND, qkvs);
    transpose_kernel<<<dim3(ND / 32, ND / 32, NL), tb, 0, stream>>>(
        Wv, wqkvT + (size_t)1536 * ND, ND, ND, (size_t)ND * ND, qkvs);
    transpose_kernel<<<dim3(ND / 32, ND / 32, NL), tb, 0, stream>>>(
        Wo, woT, ND, ND, (size_t)ND * ND, (size_t)ND * ND);
    transpose_kernel<<<dim3(NF / 32, ND / 32, NL), tb, 0, stream>>>(
        W1, w1T, ND, NF, (size_t)ND * NF, (size_t)NF * ND);
    transpose_kernel<<<dim3(ND / 32, NF / 32, NL), tb, 0, stream>>>(
        W2, w2T, NF, ND, (size_t)NF * ND, (size_t)ND * NF);
    concat_bias_kernel<<<(NL * 2304 + 255) / 256, 256, 0, stream>>>(bq, bk, bv, fb);

    for (int l = 0; l < NL; ++l) {
        gemm_v5<4><<<18 * 64, 512, 0, stream>>>(
            Xb, wqkvT + (size_t)l * qkvs, fb + (size_t)l * 2304,
            Qb, Kb, Vtb, ND, 2304, 18);
        attn_kernel<<<dim3(NH, NB, NS / 128), 256, 0, stream>>>(Qb, Kb, Vtb, vlens, Ob);
        gemm_v5<2><<<6 * 64, 512, 0, stream>>>(
            Ob, woT + (size_t)l * ND * ND, bo + l * ND,
            Yb, nullptr, nullptr, ND, ND, 6);
        ln_kernel<<<MTOK / 4, 256, 0, stream>>>(Yb, g1 + l * ND, be1 + l * ND, X, Xb);
        gemm_v5<3><<<24 * 64, 512, 0, stream>>>(
            Xb, w1T + (size_t)l * ND * NF, b1 + l * NF,
            H1, nullptr, nullptr, ND, NF, 24);
        gemm_v5<2><<<6 * 64, 512, 0, stream>>>(
            H1, w2T + (size_t)l * ND * NF, b2 + l * ND,
            Yb, nullptr, nullptr, NF, ND, 6);
        ln_kernel<<<MTOK / 4, 256, 0, stream>>>(Yb, g2 + l * ND, be2 + l * ND, X, Xb);
    }
}

// Round 11
// 2813.971 us; speedup vs baseline: 1.0240x; 1.0240x over previous
//
#include <hip/hip_runtime.h>
#include <hip/hip_bf16.h>

typedef __bf16 bf16_t;
typedef __bf16 bf16x8 __attribute__((ext_vector_type(8)));
typedef __bf16 bf16x4 __attribute__((ext_vector_type(4)));
typedef float  f32x4  __attribute__((ext_vector_type(4)));

static constexpr int ND = 768;
static constexpr int NH = 12;
static constexpr int NL = 12;
static constexpr int NF = 3072;
static constexpr int NB = 16;
static constexpr int NS = 512;
static constexpr int DH = 64;
static constexpr int MTOK = NB * NS;  // 8192 tokens

#define MFMA_BF16 __builtin_amdgcn_mfma_f32_16x16x32_bf16
#define FENCE() asm volatile("" ::: "memory")

__device__ __forceinline__ void gload16(const bf16_t* g, const bf16_t* l) {
    __builtin_amdgcn_global_load_lds(
        (const __attribute__((address_space(1))) void*)(unsigned long long)g,
        (__attribute__((address_space(3))) void*)(unsigned int)(unsigned long long)l,
        16, 0, 0);
}

// ---------------------------------------------------------------------------
__global__ __launch_bounds__(256) void embed_kernel(
    const int* __restrict__ tokens, const int* __restrict__ segments,
    const float* __restrict__ tok_emb, const float* __restrict__ seg_emb,
    const float* __restrict__ pos_emb, float* __restrict__ X,
    bf16_t* __restrict__ Xb)
{
    const int t = blockIdx.x;
    const int s = t & (NS - 1);
    const int tok = tokens[t], seg = segments[t];
    const float* te = tok_emb + (size_t)tok * ND;
    const float* se = seg_emb + (size_t)seg * ND;
    const float* pe = pos_emb + (size_t)s * ND;
#pragma unroll
    for (int i = 0; i < 3; ++i) {
        int d = threadIdx.x + i * 256;
        float v = te[d] + se[d] + pe[d];
        X[(size_t)t * ND + d]  = v;
        Xb[(size_t)t * ND + d] = (bf16_t)v;
    }
}

// ---------------------------------------------------------------------------
__global__ __launch_bounds__(256) void transpose_kernel(
    const float* __restrict__ src, bf16_t* __restrict__ dst,
    int K, int N, size_t src_stride, size_t dst_stride)
{
    __shared__ float tile[32][33];
    const float* s = src + blockIdx.z * src_stride;
    bf16_t*      d = dst + blockIdx.z * dst_stride;
    const int n0 = blockIdx.x * 32, k0 = blockIdx.y * 32;
#pragma unroll
    for (int i = threadIdx.y; i < 32; i += 8)
        tile[i][threadIdx.x] = s[(size_t)(k0 + i) * N + n0 + threadIdx.x];
    __syncthreads();
#pragma unroll
    for (int i = threadIdx.y; i < 32; i += 8)
        d[(size_t)(n0 + i) * K + k0 + threadIdx.x] = (bf16_t)tile[threadIdx.x][i];
}

__global__ __launch_bounds__(256) void concat_bias_kernel(
    const float* __restrict__ bq, const float* __restrict__ bk,
    const float* __restrict__ bv, float* __restrict__ fb)
{
    int idx = blockIdx.x * 256 + threadIdx.x;
    if (idx >= NL * 2304) return;
    int l = idx / 2304, c = idx % 2304;
    float v = (c < 768) ? bq[l * 768 + c]
            : (c < 1536) ? bk[l * 768 + c - 768] : bv[l * 768 + c - 1536];
    fb[idx] = v;
}

// ---------------------------------------------------------------------------
// GEMM v3: 128x128 tile, BK=64, dbuf global_load_lds (counted vmcnt(8)),
// both-sides XOR swizzle, XCD-chunked remap, setprio. For QKV / FFN1.
//   MODE 3: o1 = bf16(relu(v))  (FFN1)
//   MODE 4: fused QKV epilogue (region-uniform; V via LDS transpose bounce)
// ---------------------------------------------------------------------------
template <int MODE>
__global__ __launch_bounds__(256) void gemm_v3(
    const bf16_t* __restrict__ A, const bf16_t* __restrict__ Bt,
    const float* __restrict__ bias,
    bf16_t* __restrict__ o1, bf16_t* __restrict__ o2, bf16_t* __restrict__ o3,
    int K, int N, int gridN)
{
    __shared__ __align__(16) bf16_t smem[32768];  // 64 KB

    const int nwg = gridDim.x;
    const int l2 = (blockIdx.x & 7) * (nwg >> 3) + (blockIdx.x >> 3);
    const int m0 = (l2 / gridN) * 128, n0 = (l2 % gridN) * 128;

    const int tid = threadIdx.x, lane = tid & 63, wid = tid >> 6;
    const int wr = (wid >> 1) * 64, wc = (wid & 1) * 64;
    const int fr = lane & 15, g = lane >> 4;
    const int sr = lane >> 3;
    const int ssw = ((lane & 7) ^ sr) * 8;

    f32x4 acc[4][4] = {};
    const int nk = K >> 6;

    auto stage = [&](int buf, int kt) {
        const int k0 = kt << 6;
        bf16_t* Ad = smem + buf * 8192;
        bf16_t* Bd = smem + 16384 + buf * 8192;
#pragma unroll
        for (int i = 0; i < 4; ++i) {
            const int lr = wid * 32 + i * 8;
            gload16(A + (size_t)(m0 + lr + sr) * K + k0 + ssw, Ad + lr * 64);
        }
#pragma unroll
        for (int i = 0; i < 4; ++i) {
            const int lr = wid * 32 + i * 8;
            gload16(Bt + (size_t)(n0 + lr + sr) * K + k0 + ssw, Bd + lr * 64);
        }
    };

    stage(0, 0);
    for (int kt = 0; kt < nk; ++kt) {
        const int cur = kt & 1;
        if (kt + 1 < nk) {
            stage(cur ^ 1, kt + 1);
            asm volatile("s_waitcnt vmcnt(8)" ::: "memory");
        } else {
            asm volatile("s_waitcnt vmcnt(0)" ::: "memory");
        }
        FENCE(); __builtin_amdgcn_s_barrier(); FENCE();
        const bf16_t* Ab = smem + cur * 8192;
        const bf16_t* Bb = smem + 16384 + cur * 8192;
#pragma unroll
        for (int kk = 0; kk < 2; ++kk) {
            bf16x8 af[4], bfv[4];
#pragma unroll
            for (int m = 0; m < 4; ++m) {
                const int row = wr + m * 16 + fr;
                af[m] = *(const bf16x8*)(
                    &Ab[row * 64 + (((kk * 4 + g) ^ (fr & 7)) * 8)]);
            }
#pragma unroll
            for (int n = 0; n < 4; ++n) {
                const int row = wc + n * 16 + fr;
                bfv[n] = *(const bf16x8*)(
                    &Bb[row * 64 + (((kk * 4 + g) ^ (fr & 7)) * 8)]);
            }
            __builtin_amdgcn_s_setprio(1);
#pragma unroll
            for (int m = 0; m < 4; ++m)
#pragma unroll
                for (int n = 0; n < 4; ++n)
                    acc[m][n] = MFMA_BF16(af[m], bfv[n], acc[m][n], 0, 0, 0);
            __builtin_amdgcn_s_setprio(0);
        }
        FENCE(); __builtin_amdgcn_s_barrier(); FENCE();
    }

    const int rr = (lane >> 4) * 4, cc = lane & 15;

    if constexpr (MODE == 4) {
        if (n0 >= 1536) {
            // ---- V region: LDS transpose bounce -> coalesced [b][h][dh][s] ----
            bf16_t* vt = smem;
#pragma unroll
            for (int m = 0; m < 4; ++m)
#pragma unroll
                for (int n = 0; n < 4; ++n) {
                    const int cl = wc + n * 16 + cc;
                    const float bv_ = bias[n0 + cl];
#pragma unroll
                    for (int j = 0; j < 4; ++j)
                        vt[cl * 136 + (wr + m * 16 + rr + j)] =
                            (bf16_t)(acc[m][n][j] + bv_);
                }
            __syncthreads();
            const int r = tid >> 1, half = tid & 1;
            const int c = n0 - 1536 + r;
            const int hh = c >> 6, dh = c & (DH - 1);
            const int b = m0 >> 9, s0 = m0 & (NS - 1);
            bf16_t* dst = o3 + (((size_t)(b * NH + hh)) * DH + dh) * NS + s0 + half * 64;
            const bf16_t* srcp = vt + r * 136 + half * 64;
#pragma unroll
            for (int k2 = 0; k2 < 8; ++k2)
                *(bf16x8*)(dst + k2 * 8) = *(const bf16x8*)(srcp + k2 * 8);
            return;
        }
        // ---- Q or K region: direct coalesced store ----
        bf16_t* dst = (n0 < 768) ? o1 : o2;
        const int nadj = (n0 < 768) ? n0 : n0 - 768;
#pragma unroll
        for (int m = 0; m < 4; ++m)
#pragma unroll
            for (int n = 0; n < 4; ++n)
#pragma unroll
                for (int j = 0; j < 4; ++j) {
                    const int row = m0 + wr + m * 16 + rr + j;
                    const int col = wc + n * 16 + cc;
                    dst[(size_t)row * 768 + nadj + col] =
                        (bf16_t)(acc[m][n][j] + bias[n0 + col]);
                }
        return;
    }

#pragma unroll
    for (int m = 0; m < 4; ++m)
#pragma unroll
        for (int n = 0; n < 4; ++n)
#pragma unroll
            for (int j = 0; j < 4; ++j) {
                const int row = m0 + wr + m * 16 + rr + j;
                const int col = n0 + wc + n * 16 + cc;
                const float v = acc[m][n][j] + bias[col];
                o1[(size_t)row * N + col] = (bf16_t)fmaxf(v, 0.0f);  // MODE 3
            }
}

// ---------------------------------------------------------------------------
// GEMM v96: 128x96 tile (grid 8*64 = 512 = exact machine fill for N=768),
// BK=64, dbuf global_load_lds (counted vmcnt(7)), both-sides XOR swizzle,
// XCD-chunked remap, setprio. 4 waves: 2M x 2N of 64x48. For O-proj / FFN2.
// Epilogue: o1 = bf16(v) (raw out; resid-add fused into LN).
// ---------------------------------------------------------------------------
__global__ __launch_bounds__(256) void gemm_v96(
    const bf16_t* __restrict__ A, const bf16_t* __restrict__ Bt,
    const float* __restrict__ bias, bf16_t* __restrict__ o1,
    int K, int N, int gridN)
{
    __shared__ __align__(16) bf16_t smem[28672];  // A 2x8192 + B 2x6144 = 56KB

    const int nwg = gridDim.x;
    const int l2 = (blockIdx.x & 7) * (nwg >> 3) + (blockIdx.x >> 3);
    const int m0 = (l2 / gridN) * 128, n0 = (l2 % gridN) * 96;

    const int tid = threadIdx.x, lane = tid & 63, wid = tid >> 6;
    const int wr = (wid >> 1) * 64, wc = (wid & 1) * 48;
    const int fr = lane & 15, g = lane >> 4;
    const int sr = lane >> 3;
    const int ssw = ((lane & 7) ^ sr) * 8;

    f32x4 acc[4][3] = {};
    const int nk = K >> 6;

    auto stage = [&](int buf, int kt) {
        const int k0 = kt << 6;
        bf16_t* Ad = smem + buf * 8192;
        bf16_t* Bd = smem + 16384 + buf * 6144;
#pragma unroll
        for (int i = 0; i < 4; ++i) {
            const int lr = wid * 32 + i * 8;
            gload16(A + (size_t)(m0 + lr + sr) * K + k0 + ssw, Ad + lr * 64);
        }
#pragma unroll
        for (int i = 0; i < 3; ++i) {
            const int lr = wid * 24 + i * 8;
            gload16(Bt + (size_t)(n0 + lr + sr) * K + k0 + ssw, Bd + lr * 64);
        }
    };

    stage(0, 0);
    for (int kt = 0; kt < nk; ++kt) {
        const int cur = kt & 1;
        if (kt + 1 < nk) {
            stage(cur ^ 1, kt + 1);
            asm volatile("s_waitcnt vmcnt(7)" ::: "memory");
        } else {
            asm volatile("s_waitcnt vmcnt(0)" ::: "memory");
        }
        FENCE(); __builtin_amdgcn_s_barrier(); FENCE();
        const bf16_t* Ab = smem + cur * 8192;
        const bf16_t* Bb = smem + 16384 + cur * 6144;
#pragma unroll
        for (int kk = 0; kk < 2; ++kk) {
            bf16x8 af[4], bfv[3];
#pragma unroll
            for (int m = 0; m < 4; ++m) {
                const int row = wr + m * 16 + fr;
                af[m] = *(const bf16x8*)(
                    &Ab[row * 64 + (((kk * 4 + g) ^ (fr & 7)) * 8)]);
            }
#pragma unroll
            for (int n = 0; n < 3; ++n) {
                const int row = wc + n * 16 + fr;
                bfv[n] = *(const bf16x8*)(
                    &Bb[row * 64 + (((kk * 4 + g) ^ (fr & 7)) * 8)]);
            }
            __builtin_amdgcn_s_setprio(1);
#pragma unroll
            for (int m = 0; m < 4; ++m)
#pragma unroll
                for (int n = 0; n < 3; ++n)
                    acc[m][n] = MFMA_BF16(af[m], bfv[n], acc[m][n], 0, 0, 0);
            __builtin_amdgcn_s_setprio(0);
        }
        FENCE(); __builtin_amdgcn_s_barrier(); FENCE();
    }

    const int rr = (lane >> 4) * 4, cc = lane & 15;
#pragma unroll
    for (int m = 0; m < 4; ++m)
#pragma unroll
        for (int n = 0; n < 3; ++n)
#pragma unroll
            for (int j = 0; j < 4; ++j) {
                const int row = m0 + wr + m * 16 + rr + j;
                const int col = n0 + wc + n * 16 + cc;
                o1[(size_t)row * N + col] = (bf16_t)(acc[m][n][j] + bias[col]);
            }
}

// ---------------------------------------------------------------------------
// Flash attention: block = 128 q-rows of one (b,h); 4 waves x 32 rows.
// ---------------------------------------------------------------------------
__global__ __launch_bounds__(256) void attn_kernel(
    const bf16_t* __restrict__ Q, const bf16_t* __restrict__ K,
    const bf16_t* __restrict__ Vt, const int* __restrict__ vlens,
    bf16_t* __restrict__ O)
{
    const int h = blockIdx.x, b = blockIdx.y, qb = blockIdx.z;
    const int wid = threadIdx.x >> 6, lane = threadIdx.x & 63;
    const int q0 = qb * 128 + wid * 32;
    const int vl = vlens[b];
    const int fr = lane & 15, g = lane >> 4, g8 = g * 8;

    __shared__ __align__(16) bf16_t Ks[2][64 * 64];
    __shared__ __align__(16) bf16_t Vs[2][64 * 64];
    __shared__ __align__(16) bf16_t Plds[4][32 * 72];
    bf16_t* pl = Plds[wid];

    const bf16_t* kbase = K + ((size_t)(b * NS) * ND + h * DH);
    const bf16_t* vbase = Vt + ((size_t)(b * NH + h) * DH) * NS;  // [dh][s]

    bf16x8 qf[2][2];
#pragma unroll
    for (int qg = 0; qg < 2; ++qg) {
        const bf16_t* qptr = Q + ((size_t)(b * NS + q0 + qg * 16 + fr) * ND + h * DH);
        qf[qg][0] = *(const bf16x8*)(qptr + g8);
        qf[qg][1] = *(const bf16x8*)(qptr + 32 + g8);
    }
    asm volatile("s_waitcnt vmcnt(0)" ::: "memory");

    f32x4 acc_o[2][4] = {};
    float mrow[2][4], lrow[2][4];
#pragma unroll
    for (int qg = 0; qg < 2; ++qg)
#pragma unroll
        for (int j = 0; j < 4; ++j) { mrow[qg][j] = -1e30f; lrow[qg][j] = 0.f; }

    auto stage = [&](int buf, int t) {
        const int kv0 = t * 64;
#pragma unroll
        for (int i = 0; i < 2; ++i) {
            const int lr = wid * 16 + i * 8;
            const int r  = lr + (lane >> 3);
            const int ss = ((lane & 7) ^ (r & 7)) * 8;
            gload16(kbase + (size_t)(kv0 + r) * ND + ss, &Ks[buf][lr * 64]);
            gload16(vbase + (size_t)r * NS + kv0 + ss,   &Vs[buf][lr * 64]);
        }
    };

    stage(0, 0);
    for (int t = 0; t < 8; ++t) {
        const int cur = t & 1;
        const int kv0 = t * 64;
        if (t < 7) {
            stage(cur ^ 1, t + 1);
            asm volatile("s_waitcnt vmcnt(4)" ::: "memory");
        } else {
            asm volatile("s_waitcnt vmcnt(0)" ::: "memory");
        }
        FENCE(); __builtin_amdgcn_s_barrier(); FENCE();

        const bf16_t* ks = Ks[cur];
        const bf16_t* vs = Vs[cur];

        f32x4 sc[2][4];
#pragma unroll
        for (int qg = 0; qg < 2; ++qg)
#pragma unroll
            for (int f = 0; f < 4; ++f) sc[qg][f] = (f32x4){0.f, 0.f, 0.f, 0.f};
        __builtin_amdgcn_s_setprio(1);
#pragma unroll
        for (int f = 0; f < 4; ++f) {
            const int row = f * 16 + fr;
            const bf16_t* kr = ks + row * 64;
            bf16x8 kf0 = *(const bf16x8*)(kr + ((g ^ (row & 7)) * 8));
            bf16x8 kf1 = *(const bf16x8*)(kr + (((g + 4) ^ (row & 7)) * 8));
            sc[0][f] = MFMA_BF16(qf[0][0], kf0, sc[0][f], 0, 0, 0);
            sc[0][f] = MFMA_BF16(qf[0][1], kf1, sc[0][f], 0, 0, 0);
            sc[1][f] = MFMA_BF16(qf[1][0], kf0, sc[1][f], 0, 0, 0);
            sc[1][f] = MFMA_BF16(qf[1][1], kf1, sc[1][f], 0, 0, 0);
        }
        __builtin_amdgcn_s_setprio(0);

#pragma unroll
        for (int qg = 0; qg < 2; ++qg) {
            float sv[16];
#pragma unroll
            for (int f = 0; f < 4; ++f) {
                const int col = kv0 + f * 16 + fr;
                const bool masked = col >= vl;
#pragma unroll
                for (int j = 0; j < 4; ++j)
                    sv[f * 4 + j] = masked ? -1e6f : sc[qg][f][j] * 0.125f;
            }
            float pm[4], rs[4], scl[4];
#pragma unroll
            for (int j = 0; j < 4; ++j)
                pm[j] = fmaxf(fmaxf(sv[j], sv[4 + j]), fmaxf(sv[8 + j], sv[12 + j]));
#pragma unroll
            for (int msk = 1; msk < 16; msk <<= 1)
#pragma unroll
                for (int j = 0; j < 4; ++j) pm[j] = fmaxf(pm[j], __shfl_xor(pm[j], msk));
#pragma unroll
            for (int j = 0; j < 4; ++j) {
                const float mnew = fmaxf(mrow[qg][j], pm[j]);
                scl[j] = __expf(mrow[qg][j] - mnew);
                mrow[qg][j] = mnew;
                rs[j] = 0.f;
            }
#pragma unroll
            for (int f = 0; f < 4; ++f)
#pragma unroll
                for (int j = 0; j < 4; ++j) {
                    const float pv = __expf(sv[f * 4 + j] - mrow[qg][j]);
                    rs[j] += pv;
                    pl[(qg * 16 + g * 4 + j) * 72 + f * 16 + fr] = (bf16_t)pv;
                }
#pragma unroll
            for (int msk = 1; msk < 16; msk <<= 1)
#pragma unroll
                for (int j = 0; j < 4; ++j) rs[j] += __shfl_xor(rs[j], msk);
#pragma unroll
            for (int j = 0; j < 4; ++j) {
                lrow[qg][j] = lrow[qg][j] * scl[j] + rs[j];
#pragma unroll
                for (int n = 0; n < 4; ++n) acc_o[qg][n][j] *= scl[j];
            }
        }

        bf16x8 pf[2][2];
#pragma unroll
        for (int qg = 0; qg < 2; ++qg)
#pragma unroll
            for (int c = 0; c < 2; ++c)
                pf[qg][c] = *(const bf16x8*)(pl + (qg * 16 + fr) * 72 + c * 32 + g8);
        __builtin_amdgcn_s_setprio(1);
#pragma unroll
        for (int n = 0; n < 4; ++n) {
            const int row = n * 16 + fr;
            const bf16_t* vr = vs + row * 64;
            bf16x8 vf0 = *(const bf16x8*)(vr + ((g ^ (row & 7)) * 8));
            bf16x8 vf1 = *(const bf16x8*)(vr + (((g + 4) ^ (row & 7)) * 8));
            acc_o[0][n] = MFMA_BF16(pf[0][0], vf0, acc_o[0][n], 0, 0, 0);
            acc_o[0][n] = MFMA_BF16(pf[0][1], vf1, acc_o[0][n], 0, 0, 0);
            acc_o[1][n] = MFMA_BF16(pf[1][0], vf0, acc_o[1][n], 0, 0, 0);
            acc_o[1][n] = MFMA_BF16(pf[1][1], vf1, acc_o[1][n], 0, 0, 0);
        }
        __builtin_amdgcn_s_setprio(0);

        FENCE(); __builtin_amdgcn_s_barrier(); FENCE();
    }

#pragma unroll
    for (int qg = 0; qg < 2; ++qg)
#pragma unroll
        for (int n = 0; n < 4; ++n)
#pragma unroll
            for (int j = 0; j < 4; ++j) {
                const int row = q0 + qg * 16 + g * 4 + j;
                O[(size_t)(b * NS + row) * ND + h * DH + n * 16 + fr] =
                    (bf16_t)(acc_o[qg][n][j] / lrow[qg][j]);
            }
}

// ---------------------------------------------------------------------------
// Fused residual-add + LayerNorm: 1 wave per token.
// x = X + (float)Yb; stats; X = y (f32), Xb = bf16(y).
// ---------------------------------------------------------------------------
__global__ __launch_bounds__(256) void ln_kernel(
    const bf16_t* __restrict__ Yb, const float* __restrict__ g,
    const float* __restrict__ bt, float* __restrict__ X, bf16_t* __restrict__ Xb)
{
    const int wid = threadIdx.x >> 6, lane = threadIdx.x & 63;
    const int t = blockIdx.x * 4 + wid;

    const bf16_t* yp = Yb + (size_t)t * ND + lane * 12;
    bf16x4 ya = *(const bf16x4*)(yp);
    bf16x4 yb_ = *(const bf16x4*)(yp + 4);
    bf16x4 yc = *(const bf16x4*)(yp + 8);

    float* xp = X + (size_t)t * ND + lane * 12;
    f32x4 v0 = *(const f32x4*)(xp);
    f32x4 v1 = *(const f32x4*)(xp + 4);
    f32x4 v2 = *(const f32x4*)(xp + 8);

    float x[12];
#pragma unroll
    for (int i = 0; i < 4; ++i) {
        x[i]     = v0[i] + (float)ya[i];
        x[4 + i] = v1[i] + (float)yb_[i];
        x[8 + i] = v2[i] + (float)yc[i];
    }

    float s = 0.f, ss = 0.f;
#pragma unroll
    for (int i = 0; i < 12; ++i) { s += x[i]; ss += x[i] * x[i]; }
#pragma unroll
    for (int m = 1; m < 64; m <<= 1) {
        s += __shfl_xor(s, m);
        ss += __shfl_xor(ss, m);
    }
    const float mean = s * (1.0f / ND);
    const float var = ss * (1.0f / ND) - mean * mean;
    const float inv = rsqrtf(var + 1e-5f);

    const float* gp = g + lane * 12;
    const float* bp = bt + lane * 12;
    f32x4 g0 = *(const f32x4*)(gp), g1 = *(const f32x4*)(gp + 4),
          g2 = *(const f32x4*)(gp + 8);
    f32x4 b0 = *(const f32x4*)(bp), b1 = *(const f32x4*)(bp + 4),
          b2 = *(const f32x4*)(bp + 8);

    float y[12];
#pragma unroll
    for (int i = 0; i < 4; ++i) {
        y[i]     = (x[i]     - mean) * inv * g0[i] + b0[i];
        y[4 + i] = (x[4 + i] - mean) * inv * g1[i] + b1[i];
        y[8 + i] = (x[8 + i] - mean) * inv * g2[i] + b2[i];
    }

    f32x4 o0, o1v, o2v;
#pragma unroll
    for (int i = 0; i < 4; ++i) { o0[i] = y[i]; o1v[i] = y[4 + i]; o2v[i] = y[8 + i]; }
    *(f32x4*)(xp)     = o0;
    *(f32x4*)(xp + 4) = o1v;
    *(f32x4*)(xp + 8) = o2v;

    bf16x4 q0, q1, q2;
#pragma unroll
    for (int i = 0; i < 4; ++i) {
        q0[i] = (bf16_t)y[i]; q1[i] = (bf16_t)y[4 + i]; q2[i] = (bf16_t)y[8 + i];
    }
    bf16_t* xb = Xb + (size_t)t * ND + lane * 12;
    *(bf16x4*)(xb)     = q0;
    *(bf16x4*)(xb + 4) = q1;
    *(bf16x4*)(xb + 8) = q2;
}

// ---------------------------------------------------------------------------
extern "C" void kernel_launch(void* const* d_in, const int* in_sizes, int n_in,
                              void* d_out, int out_size, void* d_ws, size_t ws_size,
                              hipStream_t stream)
{
    (void)in_sizes; (void)n_in; (void)out_size; (void)ws_size;
    const int*   tokens   = (const int*)d_in[0];
    const int*   segments = (const int*)d_in[1];
    const int*   vlens    = (const int*)d_in[2];
    const float* tok_emb  = (const float*)d_in[3];
    const float* seg_emb  = (const float*)d_in[4];
    const float* pos_emb  = (const float*)d_in[5];
    const float* Wq = (const float*)d_in[6];  const float* bq = (const float*)d_in[7];
    const float* Wk = (const float*)d_in[8];  const float* bk = (const float*)d_in[9];
    const float* Wv = (const float*)d_in[10]; const float* bv = (const float*)d_in[11];
    const float* Wo = (const float*)d_in[12]; const float* bo = (const float*)d_in[13];
    const float* W1 = (const float*)d_in[14]; const float* b1 = (const float*)d_in[15];
    const float* W2 = (const float*)d_in[16]; const float* b2 = (const float*)d_in[17];
    const float* g1 = (const float*)d_in[18]; const float* be1 = (const float*)d_in[19];
    const float* g2 = (const float*)d_in[20]; const float* be2 = (const float*)d_in[21];

    float* X = (float*)d_out;

    char* p = (char*)d_ws;
    auto carve = [&](size_t elems, size_t esz) {
        void* r = (void*)p;
        p += (elems * esz + 255) & ~(size_t)255;
        return r;
    };
    bf16_t* wqkvT = (bf16_t*)carve((size_t)NL * 2304 * ND, 2);
    bf16_t* woT   = (bf16_t*)carve((size_t)NL * ND * ND, 2);
    bf16_t* w1T   = (bf16_t*)carve((size_t)NL * NF * ND, 2);
    bf16_t* w2T   = (bf16_t*)carve((size_t)NL * ND * NF, 2);
    float*  fb    = (float*)carve((size_t)NL * 2304, 4);
    bf16_t* Xb    = (bf16_t*)carve((size_t)MTOK * ND, 2);
    bf16_t* Qb    = (bf16_t*)carve((size_t)MTOK * ND, 2);
    bf16_t* Kb    = (bf16_t*)carve((size_t)MTOK * ND, 2);
    bf16_t* Vtb   = (bf16_t*)carve((size_t)MTOK * ND, 2);
    bf16_t* Ob    = (bf16_t*)carve((size_t)MTOK * ND, 2);
    bf16_t* H1    = (bf16_t*)carve((size_t)MTOK * NF, 2);
    bf16_t* Yb    = (bf16_t*)carve((size_t)MTOK * ND, 2);

    embed_kernel<<<MTOK, 256, 0, stream>>>(tokens, segments, tok_emb, seg_emb,
                                           pos_emb, X, Xb);
    const dim3 tb(32, 8);
    const size_t qkvs = (size_t)2304 * ND;
    transpose_kernel<<<dim3(ND / 32, ND / 32, NL), tb, 0, stream>>>(
        Wq, wqkvT, ND, ND, (size_t)ND * ND, qkvs);
    transpose_kernel<<<dim3(ND / 32, ND / 32, NL), tb, 0, stream>>>(
        Wk, wqkvT + (size_t)768 * ND, ND, ND, (size_t)ND * ND, qkvs);
    transpose_kernel<<<dim3(ND / 32, ND / 32, NL), tb, 0, stream>>>(
        Wv, wqkvT + (size_t)1536 * ND, ND, ND, (size_t)ND * ND, qkvs);
    transpose_kernel<<<dim3(ND / 32, ND / 32, NL), tb, 0, stream>>>(
        Wo, woT, ND, ND, (size_t)ND * ND, (size_t)ND * ND);
    transpose_kernel<<<dim3(NF / 32, ND / 32, NL), tb, 0, stream>>>(
        W1, w1T, ND, NF, (size_t)ND * NF, (size_t)NF * ND);
    transpose_kernel<<<dim3(ND / 32, NF / 32, NL), tb, 0, stream>>>(
        W2, w2T, NF, ND, (size_t)NF * ND, (size_t)ND * NF);
    concat_bias_kernel<<<(NL * 2304 + 255) / 256, 256, 0, stream>>>(bq, bk, bv, fb);

    for (int l = 0; l < NL; ++l) {
        gemm_v3<4><<<18 * 64, 256, 0, stream>>>(
            Xb, wqkvT + (size_t)l * qkvs, fb + (size_t)l * 2304,
            Qb, Kb, Vtb, ND, 2304, 18);
        attn_kernel<<<dim3(NH, NB, NS / 128), 256, 0, stream>>>(Qb, Kb, Vtb, vlens, Ob);
        gemm_v96<<<8 * 64, 256, 0, stream>>>(
            Ob, woT + (size_t)l * ND * ND, bo + l * ND, Yb, ND, ND, 8);
        ln_kernel<<<MTOK / 4, 256, 0, stream>>>(Yb, g1 + l * ND, be1 + l * ND, X, Xb);
        gemm_v3<3><<<24 * 64, 256, 0, stream>>>(
            Xb, w1T + (size_t)l * ND * NF, b1 + l * NF,
            H1, nullptr, nullptr, ND, NF, 24);
        gemm_v96<<<8 * 64, 256, 0, stream>>>(
            H1, w2T + (size_t)l * ND * NF, b2 + l * ND, Yb, NF, ND, 8);
        ln_kernel<<<MTOK / 4, 256, 0, stream>>>(Yb, g2 + l * ND, be2 + l * ND, X, Xb);
    }
}